// Round 5
// baseline (150.916 us; speedup 1.0000x reference)
//
#include <hip/hip_runtime.h>
#include <math.h>

#define BT    34   // sequence length
#define TPR   9    // threads per row; thread j owns tokens {j, j+9, j+18, j+27(<34)}
#define RPB   7    // rows per block (7*9 = 63 active threads of 64)
#define BLOCK 64   // single-wave blocks: barriers are intra-wave (cheap)

typedef float v2f __attribute__((ext_vector_type(2)));
typedef float v4f __attribute__((ext_vector_type(4)));

// log2(e)/sqrt(3): folds the 1/sqrt(hd) scale AND the exp->exp2 conversion into q.
#define QSCALE 0.83294037332470f

#if __has_builtin(__builtin_amdgcn_exp2f)
#define EXP2(x) __builtin_amdgcn_exp2f(x)
#else
#define EXP2(x) exp2f(x)
#endif

__device__ __forceinline__ void ln6(const float* x, const float* g, const float* b, float* o) {
  float mu = (x[0]+x[1]+x[2]+x[3]+x[4]+x[5]) * (1.0f/6.0f);
  float v = 0.f;
  #pragma unroll
  for (int c = 0; c < 6; ++c) { float d = x[c]-mu; v += d*d; }
  float inv = rsqrtf(v * (1.0f/6.0f) + 1e-5f);
  #pragma unroll
  for (int c = 0; c < 6; ++c) o[c] = (x[c]-mu)*inv*g[c] + b[c];
}

__global__ __launch_bounds__(BLOCK, 2)
void addtrans_kernel(const int* __restrict__ idx,
                     const float* __restrict__ tok_emb,
                     const float* __restrict__ pos_params,
                     const float* __restrict__ z10_enc,
                     const float* __restrict__ special_enc,
                     const float* __restrict__ wq,
                     const float* __restrict__ wk,
                     const float* __restrict__ wv,
                     const float* __restrict__ wo,
                     const float* __restrict__ ln1_g, const float* __restrict__ ln1_b,
                     const float* __restrict__ ln2_g, const float* __restrict__ ln2_b,
                     const float* __restrict__ lnf_g, const float* __restrict__ lnf_b,
                     const float* __restrict__ ffn_w1, const float* __restrict__ ffn_b1,
                     const float* __restrict__ ffn_w2, const float* __restrict__ ffn_b2,
                     const float* __restrict__ head_w,
                     float* __restrict__ out, int B)
{
  // kv phase: first RPB*34*12 = 2856 floats (head-interleaved); logits phase: RPB*34*14 = 3332
  __shared__ __align__(16) float s_mem[RPB*BT*14];
  __shared__ int   s_idx[RPB*BT];
  __shared__ float s_te[42];
  __shared__ float s_pos[BT*3];
  __shared__ float s_wq[18], s_wk[18], s_wv[18], s_wo[36], s_hw[18];
  __shared__ float s_g1[6], s_b1[6], s_g2[6], s_b2[6], s_gf[6], s_bf[6];
  __shared__ float s_w1[12], s_w2[12], s_fb1[2], s_fb2[6];

  const int tid = threadIdx.x;
  const int b0  = blockIdx.x * RPB;
  int nrows = B - b0; if (nrows > RPB) nrows = RPB; if (nrows < 0) nrows = 0;

  // ---- stage params / idx / build pos table ----
  if (tid < 42) s_te[tid] = tok_emb[tid];
  if (tid < 18) { s_wq[tid]=wq[tid]; s_wk[tid]=wk[tid]; s_wv[tid]=wv[tid]; s_hw[tid]=head_w[tid]; }
  if (tid < 36) s_wo[tid] = wo[tid];
  if (tid < 12) { s_w1[tid]=ffn_w1[tid]; s_w2[tid]=ffn_w2[tid]; }
  if (tid < 6)  { s_g1[tid]=ln1_g[tid]; s_b1[tid]=ln1_b[tid];
                  s_g2[tid]=ln2_g[tid]; s_b2[tid]=ln2_b[tid];
                  s_gf[tid]=lnf_g[tid]; s_bf[tid]=lnf_b[tid];
                  s_fb2[tid]=ffn_b2[tid]; }
  if (tid < 2)  s_fb1[tid] = ffn_b1[tid];
  for (int i = tid; i < nrows*BT; i += BLOCK) s_idx[i] = idx[b0*BT + i];
  if (tid < BT) {
    int p = tid, f;
    if (p < 10) f = p;
    else if (p == 10) f = 11;
    else if (p < 21) f = p - 11;
    else if (p == 21) f = 12;
    else if (p < 33) { int z = p - 22; f = (z < 10) ? z : 10; }
    else f = 13;
    float e0, e1, e2;
    if (f < 10) {
      float amp = pos_params[0], ph = pos_params[1], sl = pos_params[2], of = pos_params[3];
      float ang = 0.62831853071795864769f * (float)f + ph;  // 2*pi*f/10 + phase
      e0 = amp * cosf(ang); e1 = amp * sinf(ang); e2 = sl * (float)f + of;
    } else if (f == 10) { e0 = z10_enc[0]; e1 = z10_enc[1]; e2 = z10_enc[2]; }
    else { int u = f - 11; e0 = special_enc[u*3]; e1 = special_enc[u*3+1]; e2 = special_enc[u*3+2]; }
    s_pos[tid*3+0] = e0; s_pos[tid*3+1] = e1; s_pos[tid*3+2] = e2;
  }
  __syncthreads();

  const int row = tid / TPR;           // 0..7 (7 => lane 63, inactive)
  const int j   = tid - row * TPR;     // 0..8
  const bool active = (row < RPB) && (row < nrows);
  const bool has3 = (j < 7);           // token j+27 exists only for j<7

  v2f qp[4][3];                        // packed (head0,head1) per dim, scaled
  int vid[4];
  int tok[4];
  tok[0] = j; tok[1] = j + 9; tok[2] = j + 18; tok[3] = has3 ? (j + 27) : 33;

  // ---- embed + ln1 + qkv for 4 owned tokens; publish interleaved k,v to LDS ----
  if (active) {
    #pragma unroll
    for (int s = 0; s < 4; ++s) {
      const int t = tok[s];
      vid[s] = s_idx[row*BT + t];
      float x6[6];
      x6[0] = s_te[vid[s]*3+0]; x6[1] = s_te[vid[s]*3+1]; x6[2] = s_te[vid[s]*3+2];
      x6[3] = s_pos[t*3+0];     x6[4] = s_pos[t*3+1];     x6[5] = s_pos[t*3+2];
      float h[6];
      ln6(x6, s_g1, s_b1, h);
      float q6[6], k6[6], v6[6];
      #pragma unroll
      for (int c = 0; c < 6; ++c) {
        q6[c] = h[3]*s_wq[c] + h[4]*s_wq[6+c] + h[5]*s_wq[12+c];
        k6[c] = h[3]*s_wk[c] + h[4]*s_wk[6+c] + h[5]*s_wk[12+c];
        v6[c] = h[0]*s_wv[c] + h[1]*s_wv[6+c] + h[2]*s_wv[12+c];
      }
      qp[s][0] = (v2f){q6[0]*QSCALE, q6[3]*QSCALE};
      qp[s][1] = (v2f){q6[1]*QSCALE, q6[4]*QSCALE};
      qp[s][2] = (v2f){q6[2]*QSCALE, q6[5]*QSCALE};
      // s==3 for j>=7 duplicates token 33's kv with identical values: benign
      v4f* kvp = (v4f*)&s_mem[(row*BT + t)*12];
      kvp[0] = (v4f){k6[0], k6[3], k6[1], k6[4]};
      kvp[1] = (v4f){k6[2], k6[5], v6[0], v6[3]};
      kvp[2] = (v4f){v6[1], v6[4], v6[2], v6[5]};
    }
  }
  __syncthreads();

  // ---- causal attention: 4 segments, each kv read serves up to 4 queries ----
  v2f l[4]; v2f o[4][3];
  #pragma unroll
  for (int s = 0; s < 4; ++s) {
    l[s] = (v2f){0.f,0.f};
    o[s][0] = (v2f){0.f,0.f}; o[s][1] = (v2f){0.f,0.f}; o[s][2] = (v2f){0.f,0.f};
  }

#define LOADKV \
    v4f A = kvb[k*3+0], Bv = kvb[k*3+1], C = kvb[k*3+2]; \
    v2f kA = (v2f){A.x, A.y}, kB = (v2f){A.z, A.w}, kC = (v2f){Bv.x, Bv.y}; \
    v2f vA = (v2f){Bv.z, Bv.w}, vB = (v2f){C.x, C.y}, vC = (v2f){C.z, C.w};
#define QSTEP(s, PRED) do { \
    v2f sc = qp[s][0]*kA + qp[s][1]*kB + qp[s][2]*kC; \
    v2f p = (v2f){EXP2(sc.x), EXP2(sc.y)}; \
    if (!(PRED)) p = (v2f){0.f,0.f}; \
    l[s] += p; o[s][0] += p*vA; o[s][1] += p*vB; o[s][2] += p*vC; \
  } while(0)

  if (active) {
    const v4f* kvb = (const v4f*)&s_mem[row * (BT*12)];
    #pragma unroll 3
    for (int k = 0; k < 9; ++k) {        // q0 masked; q1,q2,q3 unmasked
      LOADKV;
      QSTEP(0, k <= j); QSTEP(1, true); QSTEP(2, true); QSTEP(3, true);
    }
    #pragma unroll 3
    for (int k = 9; k < 18; ++k) {       // q1 masked; q2,q3 unmasked
      LOADKV;
      QSTEP(1, k <= j+9); QSTEP(2, true); QSTEP(3, true);
    }
    #pragma unroll 3
    for (int k = 18; k < 27; ++k) {      // q2 masked; q3 unmasked
      LOADKV;
      QSTEP(2, k <= j+18); QSTEP(3, true);
    }
    if (has3) {
      #pragma unroll 3
      for (int k = 27; k < BT; ++k) {    // q3 masked
        LOADKV;
        QSTEP(3, k <= j+27);
      }
    }
  }
  __syncthreads();   // all kv reads done; s_mem is free for logits

  // ---- epilogue per token: o/l, wo, residual, ln2, FFN(gelu), lnf, head -> LDS ----
  if (active) {
    #pragma unroll
    for (int s = 0; s < 4; ++s) {
      if (s == 3 && !has3) continue;
      const int t = tok[s];
      const float ia = __builtin_amdgcn_rcpf(l[s].x);
      const float ib = __builtin_amdgcn_rcpf(l[s].y);
      float a6[6] = { o[s][0].x*ia, o[s][1].x*ia, o[s][2].x*ia,
                      o[s][0].y*ib, o[s][1].y*ib, o[s][2].y*ib };
      float xn[6];
      // recompute x from (vid, t) instead of carrying it in VGPRs
      float xr0 = s_te[vid[s]*3+0], xr1 = s_te[vid[s]*3+1], xr2 = s_te[vid[s]*3+2];
      float xr3 = s_pos[t*3+0],     xr4 = s_pos[t*3+1],     xr5 = s_pos[t*3+2];
      float xrv[6] = {xr0, xr1, xr2, xr3, xr4, xr5};
      #pragma unroll
      for (int c = 0; c < 6; ++c) {
        xn[c] = xrv[c]
              + a6[0]*s_wo[c]    + a6[1]*s_wo[6+c]  + a6[2]*s_wo[12+c]
              + a6[3]*s_wo[18+c] + a6[4]*s_wo[24+c] + a6[5]*s_wo[30+c];
      }
      float h2[6];
      ln6(xn, s_g2, s_b2, h2);
      float a0 = s_fb1[0], a1 = s_fb1[1];
      #pragma unroll
      for (int d = 0; d < 6; ++d) { a0 += h2[d]*s_w1[d*2]; a1 += h2[d]*s_w1[d*2+1]; }
      const float g0 = 0.5f*a0*(1.0f + erff(a0*0.70710678118654752440f));
      const float g1 = 0.5f*a1*(1.0f + erff(a1*0.70710678118654752440f));
      #pragma unroll
      for (int c = 0; c < 6; ++c) xn[c] += g0*s_w2[c] + g1*s_w2[6+c] + s_fb2[c];
      float xf[6];
      ln6(xn, s_gf, s_bf, xf);
      float y0 = 0.f, y1 = 0.f, y2 = 0.f;
      #pragma unroll
      for (int c = 0; c < 6; ++c) {
        y0 += xf[c]*s_hw[c*3+0]; y1 += xf[c]*s_hw[c*3+1]; y2 += xf[c]*s_hw[c*3+2];
      }
      // stage logits to LDS as v2f pairs (7 ds_write_b64)
      v2f* lp = (v2f*)&s_mem[(row*BT + t)*14];
      #pragma unroll
      for (int u = 0; u < 7; ++u) {
        const int c0 = 2*u, c1 = 2*u+1;
        lp[u] = (v2f){ y0*s_te[c0*3+0] + y1*s_te[c0*3+1] + y2*s_te[c0*3+2],
                       y0*s_te[c1*3+0] + y1*s_te[c1*3+1] + y2*s_te[c1*3+2] };
      }
    }
  }
  __syncthreads();

  // ---- coalesced nontemporal v4f store of the block's contiguous output ----
  if (nrows > 0) {
    const int n4 = nrows * (BT*14/4);   // 119 vec4 per row
    v4f* dst = reinterpret_cast<v4f*>(out + (size_t)b0 * (BT*14));
    const v4f* src = reinterpret_cast<const v4f*>(s_mem);
    for (int i = tid; i < n4; i += BLOCK)
      __builtin_nontemporal_store(src[i], dst + i);
  }
}

extern "C" void kernel_launch(void* const* d_in, const int* in_sizes, int n_in,
                              void* d_out, int out_size, void* d_ws, size_t ws_size,
                              hipStream_t stream) {
  const int B = in_sizes[0] / BT;                 // 32768
  const int grid = (B + RPB - 1) / RPB;           // 4682
  addtrans_kernel<<<grid, BLOCK, 0, stream>>>(
      (const int*)d_in[0],   (const float*)d_in[1], (const float*)d_in[2],
      (const float*)d_in[3], (const float*)d_in[4], (const float*)d_in[5],
      (const float*)d_in[6], (const float*)d_in[7], (const float*)d_in[8],
      (const float*)d_in[9], (const float*)d_in[10], (const float*)d_in[11],
      (const float*)d_in[12], (const float*)d_in[13], (const float*)d_in[14],
      (const float*)d_in[15], (const float*)d_in[16], (const float*)d_in[17],
      (const float*)d_in[18], (const float*)d_in[19],
      (float*)d_out, B);
}

// Round 6
// 144.043 us; speedup vs baseline: 1.0477x; 1.0477x over previous
//
#include <hip/hip_runtime.h>
#include <math.h>

#define BT    34   // sequence length
#define TPR   17   // threads per row (thread j owns tokens j and j+17)
#define RPB   15   // rows per block (15*17 = 255 active threads of 256)
#define BLOCK 256

typedef float v2f __attribute__((ext_vector_type(2)));
typedef float v4f __attribute__((ext_vector_type(4)));
typedef _Float16 h2 __attribute__((ext_vector_type(2)));

// log2(e)/sqrt(3): folds the 1/sqrt(hd) scale AND the exp->exp2 conversion into q.
#define QSCALE 0.83294037332470f

#if __has_builtin(__builtin_amdgcn_exp2f)
#define EXP2(x) __builtin_amdgcn_exp2f(x)
#else
#define EXP2(x) exp2f(x)
#endif

__device__ __forceinline__ void ln6(const float* x, const float* g, const float* b, float* o) {
  float mu = (x[0]+x[1]+x[2]+x[3]+x[4]+x[5]) * (1.0f/6.0f);
  float v = 0.f;
  #pragma unroll
  for (int c = 0; c < 6; ++c) { float d = x[c]-mu; v += d*d; }
  float inv = rsqrtf(v * (1.0f/6.0f) + 1e-5f);
  #pragma unroll
  for (int c = 0; c < 6; ++c) o[c] = (x[c]-mu)*inv*g[c] + b[c];
}

// LDS: union buffer. kv pass view: RPB*17*12 floats = 12240 B.
//      logits view: RPB*34*7 u32 (fp16 pairs) = 14280 B.  -> size = 3570 u32
__global__ __launch_bounds__(BLOCK, 6)
void addtrans_kernel(const int* __restrict__ idx,
                     const float* __restrict__ tok_emb,
                     const float* __restrict__ pos_params,
                     const float* __restrict__ z10_enc,
                     const float* __restrict__ special_enc,
                     const float* __restrict__ wq,
                     const float* __restrict__ wk,
                     const float* __restrict__ wv,
                     const float* __restrict__ wo,
                     const float* __restrict__ ln1_g, const float* __restrict__ ln1_b,
                     const float* __restrict__ ln2_g, const float* __restrict__ ln2_b,
                     const float* __restrict__ lnf_g, const float* __restrict__ lnf_b,
                     const float* __restrict__ ffn_w1, const float* __restrict__ ffn_b1,
                     const float* __restrict__ ffn_w2, const float* __restrict__ ffn_b2,
                     const float* __restrict__ head_w,
                     float* __restrict__ out, int B)
{
  __shared__ __align__(16) unsigned s_u32[RPB*BT*7];
  __shared__ float s_te[42];
  __shared__ float s_pos[BT*3];
  __shared__ float s_wq[18], s_wk[18], s_wv[18], s_wo[36], s_hw[18];
  __shared__ float s_g1[6], s_b1[6], s_g2[6], s_b2[6], s_gf[6], s_bf[6];
  __shared__ float s_w1[12], s_w2[12], s_fb1[2], s_fb2[6];

  float* s_kvf = (float*)s_u32;
  const int tid = threadIdx.x;

  // ---- stage params / build pos table ----
  if (tid < 42) s_te[tid] = tok_emb[tid];
  if (tid < 18) { s_wq[tid]=wq[tid]; s_wk[tid]=wk[tid]; s_wv[tid]=wv[tid]; s_hw[tid]=head_w[tid]; }
  if (tid < 36) s_wo[tid] = wo[tid];
  if (tid < 12) { s_w1[tid]=ffn_w1[tid]; s_w2[tid]=ffn_w2[tid]; }
  if (tid < 6)  { s_g1[tid]=ln1_g[tid]; s_b1[tid]=ln1_b[tid];
                  s_g2[tid]=ln2_g[tid]; s_b2[tid]=ln2_b[tid];
                  s_gf[tid]=lnf_g[tid]; s_bf[tid]=lnf_b[tid];
                  s_fb2[tid]=ffn_b2[tid]; }
  if (tid < 2)  s_fb1[tid] = ffn_b1[tid];
  if (tid < BT) {
    int p = tid, f;
    if (p < 10) f = p;
    else if (p == 10) f = 11;
    else if (p < 21) f = p - 11;
    else if (p == 21) f = 12;
    else if (p < 33) { int z = p - 22; f = (z < 10) ? z : 10; }
    else f = 13;
    float e0, e1, e2;
    if (f < 10) {
      float amp = pos_params[0], ph = pos_params[1], sl = pos_params[2], of = pos_params[3];
      float ang = 0.62831853071795864769f * (float)f + ph;  // 2*pi*f/10 + phase
      e0 = amp * cosf(ang); e1 = amp * sinf(ang); e2 = sl * (float)f + of;
    } else if (f == 10) { e0 = z10_enc[0]; e1 = z10_enc[1]; e2 = z10_enc[2]; }
    else { int u = f - 11; e0 = special_enc[u*3]; e1 = special_enc[u*3+1]; e2 = special_enc[u*3+2]; }
    s_pos[tid*3+0] = e0; s_pos[tid*3+1] = e1; s_pos[tid*3+2] = e2;
  }
  __syncthreads();

  const int row = tid / TPR;           // 0..15 (15 => inactive)
  const int j   = tid - row * TPR;     // 0..16
  const int b0  = blockIdx.x * RPB;
  const int b   = b0 + row;
  int nrows = B - b0; if (nrows > RPB) nrows = RPB; if (nrows < 0) nrows = 0;
  const bool active = (row < RPB) && (b < B);

  v2f   qp[2][3];                      // packed (head0,head1) per dim, scaled by QSCALE
  float h1[6];                         // ln1 output of token j+17 (for pass-2 kv republish)
  int   vid[2];

  // ---- embed + ln1 + q/k/v for both owned tokens; publish kv of token j only ----
  if (active) {
    const int base = b * BT;
    #pragma unroll
    for (int s = 0; s < 2; ++s) {
      const int t = j + s * TPR;
      vid[s] = idx[base + t];
      float x6[6];
      x6[0] = s_te[vid[s]*3+0]; x6[1] = s_te[vid[s]*3+1]; x6[2] = s_te[vid[s]*3+2];
      x6[3] = s_pos[t*3+0];     x6[4] = s_pos[t*3+1];     x6[5] = s_pos[t*3+2];
      float h[6];
      ln6(x6, s_g1, s_b1, h);
      float q6[6];
      #pragma unroll
      for (int c = 0; c < 6; ++c)
        q6[c] = h[3]*s_wq[c] + h[4]*s_wq[6+c] + h[5]*s_wq[12+c];
      qp[s][0] = (v2f){q6[0]*QSCALE, q6[3]*QSCALE};
      qp[s][1] = (v2f){q6[1]*QSCALE, q6[4]*QSCALE};
      qp[s][2] = (v2f){q6[2]*QSCALE, q6[5]*QSCALE};
      if (s == 0) {
        float k6[6], v6[6];
        #pragma unroll
        for (int c = 0; c < 6; ++c) {
          k6[c] = h[3]*s_wk[c] + h[4]*s_wk[6+c] + h[5]*s_wk[12+c];
          v6[c] = h[0]*s_wv[c] + h[1]*s_wv[6+c] + h[2]*s_wv[12+c];
        }
        v4f* kvp = (v4f*)&s_kvf[(row*TPR + j)*12];
        kvp[0] = (v4f){k6[0], k6[3], k6[1], k6[4]};
        kvp[1] = (v4f){k6[2], k6[5], v6[0], v6[3]};
        kvp[2] = (v4f){v6[1], v6[4], v6[2], v6[5]};
      } else {
        #pragma unroll
        for (int c = 0; c < 6; ++c) h1[c] = h[c];
      }
    }
  }
  __syncthreads();

  // ---- attention (exp2 domain, packed heads), two kv passes ----
  v2f l0 = (v2f){0.f,0.f}, l1 = (v2f){0.f,0.f};
  v2f o0[3] = {(v2f){0.f,0.f},(v2f){0.f,0.f},(v2f){0.f,0.f}};
  v2f o1[3] = {(v2f){0.f,0.f},(v2f){0.f,0.f},(v2f){0.f,0.f}};
  const v4f* kvb = (const v4f*)&s_kvf[row * (TPR*12)];

#define LOADKV(kk) \
    v4f A = kvb[(kk)*3+0], Bv = kvb[(kk)*3+1], C = kvb[(kk)*3+2]; \
    v2f kA = (v2f){A.x, A.y}, kB = (v2f){A.z, A.w}, kC = (v2f){Bv.x, Bv.y}; \
    v2f vA = (v2f){Bv.z, Bv.w}, vB = (v2f){C.x, C.y}, vC = (v2f){C.z, C.w};
#define QSTEP(qq, ll, oo, PRED) do { \
    v2f sc = qp[qq][0]*kA + qp[qq][1]*kB + qp[qq][2]*kC; \
    v2f p = (v2f){EXP2(sc.x), EXP2(sc.y)}; \
    if (!(PRED)) p = (v2f){0.f,0.f}; \
    ll += p; oo[0] += p*vA; oo[1] += p*vB; oo[2] += p*vC; \
  } while(0)

  if (active) {
    #pragma unroll 4
    for (int k = 0; k < TPR; ++k) {      // keys 0..16: q0 masked, q1 unmasked
      LOADKV(k);
      QSTEP(0, l0, o0, k <= j);
      QSTEP(1, l1, o1, true);
    }
  }
  __syncthreads();                       // pass-1 reads complete

  // republish kv for token j+17 into slot j (from held h1)
  if (active) {
    float k6[6], v6[6];
    #pragma unroll
    for (int c = 0; c < 6; ++c) {
      k6[c] = h1[3]*s_wk[c] + h1[4]*s_wk[6+c] + h1[5]*s_wk[12+c];
      v6[c] = h1[0]*s_wv[c] + h1[1]*s_wv[6+c] + h1[2]*s_wv[12+c];
    }
    v4f* kvp = (v4f*)&s_kvf[(row*TPR + j)*12];
    kvp[0] = (v4f){k6[0], k6[3], k6[1], k6[4]};
    kvp[1] = (v4f){k6[2], k6[5], v6[0], v6[3]};
    kvp[2] = (v4f){v6[1], v6[4], v6[2], v6[5]};
  }
  __syncthreads();                       // pass-2 kv ready

  if (active) {
    #pragma unroll 4
    for (int k2 = 0; k2 < TPR; ++k2) {   // keys 17..33 in slots 0..16: q1 masked
      LOADKV(k2);
      QSTEP(1, l1, o1, k2 <= j);         // k=k2+17 <= j+17  <=>  k2 <= j
    }
  }
  __syncthreads();                       // pass-2 reads done; buffer free for logits

  // ---- epilogue: o/l, wo, residual, ln2, FFN(exact gelu), lnf, head -> fp16 LDS ----
  if (active) {
    #pragma unroll
    for (int s = 0; s < 2; ++s) {
      const int t = j + s * TPR;
      const v2f  lv = s ? l1 : l0;
      const v2f* ov = s ? o1 : o0;
      const float ia = __builtin_amdgcn_rcpf(lv.x);
      const float ib = __builtin_amdgcn_rcpf(lv.y);
      float a6[6] = { ov[0].x*ia, ov[1].x*ia, ov[2].x*ia,
                      ov[0].y*ib, ov[1].y*ib, ov[2].y*ib };
      float xn[6];
      // recompute x from (vid, t)
      float xrv[6] = { s_te[vid[s]*3+0], s_te[vid[s]*3+1], s_te[vid[s]*3+2],
                       s_pos[t*3+0],     s_pos[t*3+1],     s_pos[t*3+2] };
      #pragma unroll
      for (int c = 0; c < 6; ++c) {
        xn[c] = xrv[c]
              + a6[0]*s_wo[c]    + a6[1]*s_wo[6+c]  + a6[2]*s_wo[12+c]
              + a6[3]*s_wo[18+c] + a6[4]*s_wo[24+c] + a6[5]*s_wo[30+c];
      }
      float h2v[6];
      ln6(xn, s_g2, s_b2, h2v);
      float a0 = s_fb1[0], a1 = s_fb1[1];
      #pragma unroll
      for (int d = 0; d < 6; ++d) { a0 += h2v[d]*s_w1[d*2]; a1 += h2v[d]*s_w1[d*2+1]; }
      const float g0 = 0.5f*a0*(1.0f + erff(a0*0.70710678118654752440f));
      const float g1 = 0.5f*a1*(1.0f + erff(a1*0.70710678118654752440f));
      #pragma unroll
      for (int c = 0; c < 6; ++c) xn[c] += g0*s_w2[c] + g1*s_w2[6+c] + s_fb2[c];
      float xf[6];
      ln6(xn, s_gf, s_bf, xf);
      float y0 = 0.f, y1 = 0.f, y2 = 0.f;
      #pragma unroll
      for (int c = 0; c < 6; ++c) {
        y0 += xf[c]*s_hw[c*3+0]; y1 += xf[c]*s_hw[c*3+1]; y2 += xf[c]*s_hw[c*3+2];
      }
      // 14 logits -> 7 packed fp16 pairs in LDS
      unsigned* lp = &s_u32[(row*BT + t)*7];
      #pragma unroll
      for (int u = 0; u < 7; ++u) {
        const int c0 = 2*u, c1 = 2*u+1;
        float f0 = y0*s_te[c0*3+0] + y1*s_te[c0*3+1] + y2*s_te[c0*3+2];
        float f1 = y0*s_te[c1*3+0] + y1*s_te[c1*3+1] + y2*s_te[c1*3+2];
        lp[u] = __builtin_bit_cast(unsigned, __builtin_amdgcn_cvt_pkrtz(f0, f1));
      }
    }
  }
  __syncthreads();

  // ---- coalesced store: read fp16 pair, convert, nontemporal b64 store ----
  if (nrows > 0) {
    const int n2 = nrows * (BT*14/2);    // u32 pairs: 238 per row
    float* dst = out + (size_t)b0 * (BT*14);
    for (int i = tid; i < n2; i += BLOCK) {
      h2 hv = __builtin_bit_cast(h2, s_u32[i]);
      v2f f = (v2f){(float)hv.x, (float)hv.y};
      __builtin_nontemporal_store(f, (v2f*)(dst + 2*i));
    }
  }
}

extern "C" void kernel_launch(void* const* d_in, const int* in_sizes, int n_in,
                              void* d_out, int out_size, void* d_ws, size_t ws_size,
                              hipStream_t stream) {
  const int B = in_sizes[0] / BT;                 // 32768
  const int grid = (B + RPB - 1) / RPB;           // 2185
  addtrans_kernel<<<grid, BLOCK, 0, stream>>>(
      (const int*)d_in[0],   (const float*)d_in[1], (const float*)d_in[2],
      (const float*)d_in[3], (const float*)d_in[4], (const float*)d_in[5],
      (const float*)d_in[6], (const float*)d_in[7], (const float*)d_in[8],
      (const float*)d_in[9], (const float*)d_in[10], (const float*)d_in[11],
      (const float*)d_in[12], (const float*)d_in[13], (const float*)d_in[14],
      (const float*)d_in[15], (const float*)d_in[16], (const float*)d_in[17],
      (const float*)d_in[18], (const float*)d_in[19],
      (float*)d_out, B);
}